// Round 3
// baseline (841.429 us; speedup 1.0000x reference)
//
#include <hip/hip_runtime.h>
#include <hip/hip_bf16.h>
#include <stdint.h>

#define B_ 8192
#define D_ 1024
#define H_ 4096
#define O_ 1024
#define E_ 8

typedef __attribute__((ext_vector_type(8))) short bf16x8;
typedef __attribute__((ext_vector_type(4))) float f32x4;

__device__ __forceinline__ ushort f2bf(float f) {
  uint32_t u = __builtin_bit_cast(uint32_t, f);
  uint32_t r = (u + 0x7FFFu + ((u >> 16) & 1u)) >> 16;
  return (ushort)r;
}

__device__ __forceinline__ void gload_lds16(const ushort* g, ushort* l) {
  __builtin_amdgcn_global_load_lds(
      (__attribute__((address_space(1))) void*)g,
      (__attribute__((address_space(3))) void*)l, 16, 0, 0);
}

// ---------------- x fp32 -> bf16 ----------------
__global__ void cvt_x_k(const float* __restrict__ x, ushort* __restrict__ xb) {
  int i = blockIdx.x * 256 + threadIdx.x;            // over B*D/4
  float4 v = ((const float4*)x)[i];
  ushort4 r;
  r.x = f2bf(v.x); r.y = f2bf(v.y); r.z = f2bf(v.z); r.w = f2bf(v.w);
  ((ushort4*)xb)[i] = r;
}

// ------------- per-expert transpose + cvt: in [E][R][C] f32 -> out [E][C][R] bf16 -------------
__global__ void transpose_cvt(const float* __restrict__ in, ushort* __restrict__ out,
                              int R, int C) {
  __shared__ ushort tile[64][66];
  int h0 = blockIdx.x * 64, d0 = blockIdx.y * 64;
  size_t eoff = (size_t)blockIdx.z * R * C;
  int t = threadIdx.x;
  int a = t & 63, q = t >> 6;
#pragma unroll
  for (int i = 0; i < 16; ++i) {
    int dl = q * 16 + i;
    tile[dl][a] = f2bf(in[eoff + (size_t)(d0 + dl) * C + h0 + a]);
  }
  __syncthreads();
#pragma unroll
  for (int i = 0; i < 16; ++i) {
    int hh = q * 16 + i;
    out[eoff + (size_t)(h0 + hh) * R + d0 + a] = tile[a][hh];
  }
}

// ---------------- gating: logits, top-2, softmax, routing prep ----------------
__global__ void gating_k(const float* __restrict__ x, const float* __restrict__ Wg,
                         const float* __restrict__ bg, float* __restrict__ gates,
                         float* __restrict__ topi, int* __restrict__ exp_a,
                         float* __restrict__ gate_a, int* __restrict__ counts) {
  int row = blockIdx.x * 4 + (threadIdx.x >> 6);
  int lane = threadIdx.x & 63;
  const float* xr = x + (size_t)row * D_;
  float acc[8];
#pragma unroll
  for (int e = 0; e < 8; ++e) acc[e] = 0.f;
  for (int j = 0; j < 16; ++j) {
    int d = j * 64 + lane;
    float xv = xr[d];
    const float4* wp = (const float4*)(Wg + d * 8);
    float4 w0 = wp[0], w1 = wp[1];
    acc[0] = fmaf(xv, w0.x, acc[0]); acc[1] = fmaf(xv, w0.y, acc[1]);
    acc[2] = fmaf(xv, w0.z, acc[2]); acc[3] = fmaf(xv, w0.w, acc[3]);
    acc[4] = fmaf(xv, w1.x, acc[4]); acc[5] = fmaf(xv, w1.y, acc[5]);
    acc[6] = fmaf(xv, w1.z, acc[6]); acc[7] = fmaf(xv, w1.w, acc[7]);
  }
#pragma unroll
  for (int e = 0; e < 8; ++e) {
#pragma unroll
    for (int off = 32; off; off >>= 1) acc[e] += __shfl_xor(acc[e], off);
  }
  if (lane == 0) {
    float v0 = -1e30f, v1 = -1e30f; int i0 = 0, i1 = 0;
#pragma unroll
    for (int e = 0; e < 8; ++e) {
      float ve = acc[e] + bg[e];
      if (ve > v0)      { v1 = v0; i1 = i0; v0 = ve; i0 = e; }
      else if (ve > v1) { v1 = ve; i1 = e; }
    }
    float t = expf(v1 - v0);
    float g0 = 1.f / (1.f + t), g1 = t / (1.f + t);
    gates[row * 8 + i0] = g0;
    gates[row * 8 + i1] = g1;
    topi[row * 2 + 0] = (float)i0;
    topi[row * 2 + 1] = (float)i1;
    exp_a[row * 2 + 0] = i0;
    exp_a[row * 2 + 1] = i1;
    gate_a[row * 2 + 0] = g0;
    gate_a[row * 2 + 1] = g1;
    atomicAdd(&counts[i0], 1);
    atomicAdd(&counts[i1], 1);
  }
}

__global__ void prefix_k(const int* __restrict__ counts, int* __restrict__ offs,
                         int* __restrict__ cursors) {
  if (threadIdx.x == 0) {
    int s = 0;
    for (int e = 0; e < 8; ++e) { offs[e] = s; cursors[e] = s; s += counts[e]; }
  }
}

__global__ void scatter_k(const int* __restrict__ exp_a, int* __restrict__ cursors,
                          int* __restrict__ rows, int* __restrict__ slot_of) {
  int a = blockIdx.x * 256 + threadIdx.x;            // 0..16383
  int e = exp_a[a];
  int slot = atomicAdd(&cursors[e], 1);
  rows[slot] = a >> 1;
  slot_of[a] = slot;
}

// ============ grouped expert GEMM: 256x256x64, 8-phase schedule (T2+T3+T4+T5) ============
// 8 waves (2M x 4N), per-wave 128x64 C. LDS = 2 buf x (A 32K + B 32K) = 128 KiB.
// K-tile = 4 phases; phase q: {ds_read A-frags (q==0: +B-frags) | stage quarter-chunk
// (2 gload_lds, 5 phases ahead) | barrier | setprio+16 MFMA | barrier}. One counted
// vmcnt(2) per K-tile (end of phase 3) -- loads stay in flight across barriers.
// WAR safety: stage at phase P overwrites data last read at phase <= P-1 (2 barriers
// between); worst case quarter-1 has exactly gap 1. RAW: vmcnt(2) leaves only the
// newest chunk (tile t+2 q0) in flight, so all of tile t+1 has landed.
template <int LAYER>
__global__ __launch_bounds__(512, 2)
void moe_gemm(const ushort* __restrict__ Abase, const ushort* __restrict__ Bbase,
              const float* __restrict__ bias, ushort* __restrict__ hout,
              float* __restrict__ part, const int* __restrict__ rows,
              const int* __restrict__ counts, const int* __restrict__ offs) {
  constexpr int KD = (LAYER == 1) ? D_ : H_;   // K dim
  constexpr int ND = (LAYER == 1) ? H_ : O_;   // N dim (rows of Bt)
  constexpr int NT = KD / 64;

  // XCD-aware bijective swizzle (nwg % 8 == 0 for both layers)
  int gx = gridDim.x, gy = gridDim.y;
  int nwg = gx * gy * (int)gridDim.z;
  int gid = blockIdx.x + gx * (blockIdx.y + gy * blockIdx.z);
  int sid = (gid & 7) * (nwg >> 3) + (gid >> 3);
  int nb = sid % gx;
  int rest = sid / gx;
  int mb = rest % gy;
  int e = rest / gy;

  int cnt = counts[e];
  int m0 = mb * 256;
  if (m0 >= cnt) return;
  int n0 = nb * 256;
  int off = offs[e];

  __shared__ __align__(16) ushort lds[65536];   // 128 KiB: buf b at b*32768 (ushorts)

  int tid = threadIdx.x;
  int wid = tid >> 6, lane = tid & 63;
  int wr = wid >> 2, wc = wid & 3;              // 2M x 4N

  // --- staging source pointers: quarter c covers tile rows c*64..c*64+63 ---
  int rl = tid >> 3;                            // 0..63: row within quarter
  int xorc = ((lane & 7) ^ (lane >> 3)) << 3;   // seg ^ (row&7), in elements
  const ushort* pA[4];
  const ushort* pB[4];
#pragma unroll
  for (int c = 0; c < 4; ++c) {
    int slot = m0 + c * 64 + rl; slot = (slot < cnt) ? slot : (cnt - 1);
    size_t arow;
    if (LAYER == 1) arow = (size_t)rows[off + slot];
    else            arow = (size_t)(off + slot);
    pA[c] = Abase + arow * KD + xorc;
    pB[c] = Bbase + ((size_t)e * ND + n0 + c * 64 + rl) * KD + xorc;
  }

  // stage one quarter-chunk (A 64x64 + B 64x64 bf16 = 16 KiB, 2 loads/thread)
  auto STAGE = [&](int c, int bb) {
    ushort* dst = lds + bb * 32768 + c * 4096 + wid * 512;
    gload_lds16(pA[c], dst);
    gload_lds16(pB[c], dst + 16384);
    pA[c] += 64; pB[c] += 64;
  };

  f32x4 acc[8][4];
  f32x4 z = {0.f, 0.f, 0.f, 0.f};
#pragma unroll
  for (int m = 0; m < 8; ++m)
#pragma unroll
    for (int n = 0; n < 4; ++n) acc[m][n] = z;

  int lrow = lane & 15;
  int lkb = (lane >> 4) << 4;        // byte offset of 8-elem k-seg within 128B row
  int swz = (lane & 7) << 4;

  // prologue: chunks 0..3 (tile 0) + chunk 4 (tile 1 q0); allow chunk 4 in flight
  STAGE(0, 0); STAGE(1, 0); STAGE(2, 0); STAGE(3, 0); STAGE(0, 1);
  asm volatile("s_waitcnt vmcnt(2)" ::: "memory");
  asm volatile("s_barrier" ::: "memory");

#pragma unroll 1
  for (int t = 0; t < NT; ++t) {
    const char* bA = (const char*)lds + (t & 1) * 65536;
    const char* bB = bA + 32768;
    bf16x8 bfr[4][2];
#pragma unroll
    for (int q = 0; q < 4; ++q) {
      bf16x8 af[2][2];
#pragma unroll
      for (int mm = 0; mm < 2; ++mm)
#pragma unroll
        for (int ks = 0; ks < 2; ++ks) {
          int r = wr * 128 + (2 * q + mm) * 16 + lrow;
          af[mm][ks] = *(const bf16x8*)(bA + r * 128 + ((ks * 64 + lkb) ^ swz));
        }
      if (q == 0) {
#pragma unroll
        for (int n = 0; n < 4; ++n)
#pragma unroll
          for (int ks = 0; ks < 2; ++ks) {
            int r = wc * 64 + n * 16 + lrow;
            bfr[n][ks] = *(const bf16x8*)(bB + r * 128 + ((ks * 64 + lkb) ^ swz));
          }
      }
      int g = 4 * t + q + 5;                     // stage 5 phases ahead
      if (g < 4 * NT) STAGE(g & 3, (g >> 2) & 1);
      asm volatile("s_barrier" ::: "memory");
      __builtin_amdgcn_s_setprio(1);
#pragma unroll
      for (int mm = 0; mm < 2; ++mm)
#pragma unroll
        for (int n = 0; n < 4; ++n)
#pragma unroll
          for (int ks = 0; ks < 2; ++ks)
            acc[2 * q + mm][n] = __builtin_amdgcn_mfma_f32_16x16x32_bf16(
                af[mm][ks], bfr[n][ks], acc[2 * q + mm][n], 0, 0, 0);
      __builtin_amdgcn_s_setprio(0);
      if (q == 3) {
        if (t < NT - 2)       asm volatile("s_waitcnt vmcnt(2)" ::: "memory");
        else if (t == NT - 2) asm volatile("s_waitcnt vmcnt(0)" ::: "memory");
      }
      asm volatile("s_barrier" ::: "memory");
    }
  }

  // --- epilogue: C/D layout col=lane&15, row=(lane>>4)*4+j ---
  const float* bias_e = bias + (size_t)e * ND;
  int colbase = n0 + wc * 64;
#pragma unroll
  for (int m = 0; m < 8; ++m) {
    int rl2 = m0 + wr * 128 + m * 16 + ((lane >> 4) << 2);
#pragma unroll
    for (int n = 0; n < 4; ++n) {
      int cg = colbase + n * 16 + (lane & 15);
      float bv = bias_e[cg];
      f32x4 a = acc[m][n];
#pragma unroll
      for (int j = 0; j < 4; ++j) {
        int r = rl2 + j;
        if (r < cnt) {
          float v = a[j] + bv;
          if (LAYER == 1) {
            v = fmaxf(v, 0.f);
            hout[(size_t)(off + r) * H_ + cg] = f2bf(v);
          } else {
            part[(size_t)(off + r) * O_ + cg] = v;
          }
        }
      }
    }
  }
}

// ---------------- combine: out[b] = g0*part[s0] + g1*part[s1] ----------------
__global__ void combine_k(const float* __restrict__ part, const int* __restrict__ slot_of,
                          const float* __restrict__ gate_a, float* __restrict__ out) {
  int i = blockIdx.x * 256 + threadIdx.x;  // over B*O/4
  int b = i >> 8;
  int c4 = i & 255;
  int s0 = slot_of[b * 2], s1 = slot_of[b * 2 + 1];
  float g0 = gate_a[b * 2], g1 = gate_a[b * 2 + 1];
  float4 p0 = ((const float4*)(part + (size_t)s0 * O_))[c4];
  float4 p1 = ((const float4*)(part + (size_t)s1 * O_))[c4];
  float4 r;
  r.x = g0 * p0.x + g1 * p1.x;
  r.y = g0 * p0.y + g1 * p1.y;
  r.z = g0 * p0.z + g1 * p1.z;
  r.w = g0 * p0.w + g1 * p1.w;
  ((float4*)(out + (size_t)b * O_))[c4] = r;
}

// ---------------- importance / load (deterministic fixed-tree reduce) ----------------
__global__ void importance_k(const float* __restrict__ gates, float* __restrict__ load,
                             float* __restrict__ imp) {
  int e = blockIdx.x;
  float s = 0.f;
  for (int b = threadIdx.x; b < B_; b += 256) s += gates[b * 8 + e];
  __shared__ float red[4];
#pragma unroll
  for (int off = 32; off; off >>= 1) s += __shfl_xor(s, off);
  if ((threadIdx.x & 63) == 0) red[threadIdx.x >> 6] = s;
  __syncthreads();
  if (threadIdx.x == 0) {
    float t = (red[0] + red[1]) + (red[2] + red[3]);
    imp[e] = t;
    load[e] = t * (1.f / (float)B_);
  }
}

extern "C" void kernel_launch(void* const* d_in, const int* in_sizes, int n_in,
                              void* d_out, int out_size, void* d_ws, size_t ws_size,
                              hipStream_t stream) {
  const float* x  = (const float*)d_in[0];
  const float* Wg = (const float*)d_in[1];
  const float* bg = (const float*)d_in[2];
  const float* W1 = (const float*)d_in[3];
  const float* b1 = (const float*)d_in[4];
  const float* W2 = (const float*)d_in[5];
  const float* b2 = (const float*)d_in[6];

  float* out = (float*)d_out;
  float* out_y     = out;                 // [B,O]  8388608
  float* out_gates = out + 8388608;       // [B,E]  65536
  float* out_load  = out + 8454144;       // [E]    8
  float* out_imp   = out + 8454152;       // [E]    8
  float* out_topi  = out + 8454160;       // [B,K]  16384 (as float)

  char* w = (char*)d_ws;
  ushort* x_bf    = (ushort*)(w);                      // 16,777,216 B
  ushort* w1t     = (ushort*)(w + 16777216);           // 67,108,864 B  [E][H][D]
  ushort* w2t     = (ushort*)(w + 83886080);           // 67,108,864 B  [E][O][H]
  ushort* h_buf   = (ushort*)(w + 150994944);          // 134,217,728 B [16384][H]
  float*  part    = (float*)(w + 285212672);           // 67,108,864 B  [16384][O]
  int*    rows    = (int*)(w + 352321536);             // 65536 B
  int*    slot_of = (int*)(w + 352387072);             // 65536 B
  int*    exp_a   = (int*)(w + 352452608);             // 65536 B
  float*  gate_a  = (float*)(w + 352518144);           // 65536 B
  int*    counts  = (int*)(w + 352583680);             // 32 B
  int*    offs    = (int*)(w + 352583712);             // 32 B
  int*    cursors = (int*)(w + 352583744);             // 32 B

  (void)in_sizes; (void)n_in; (void)out_size; (void)ws_size;

  hipMemsetAsync(out_gates, 0, 65536 * sizeof(float), stream);
  hipMemsetAsync(counts, 0, 96, stream);

  cvt_x_k<<<B_ * D_ / 4 / 256, 256, 0, stream>>>(x, x_bf);
  transpose_cvt<<<dim3(H_ / 64, D_ / 64, E_), 256, 0, stream>>>(W1, w1t, D_, H_);
  transpose_cvt<<<dim3(O_ / 64, H_ / 64, E_), 256, 0, stream>>>(W2, w2t, H_, O_);

  gating_k<<<B_ / 4, 256, 0, stream>>>(x, Wg, bg, out_gates, out_topi, exp_a, gate_a, counts);
  prefix_k<<<1, 64, 0, stream>>>(counts, offs, cursors);
  scatter_k<<<64, 256, 0, stream>>>(exp_a, cursors, rows, slot_of);

  moe_gemm<1><<<dim3(H_ / 256, 32, E_), 512, 0, stream>>>(x_bf, w1t, b1, h_buf, part,
                                                          rows, counts, offs);
  moe_gemm<2><<<dim3(O_ / 256, 32, E_), 512, 0, stream>>>(h_buf, w2t, b2, h_buf, part,
                                                          rows, counts, offs);

  combine_k<<<B_ * O_ / 4 / 256, 256, 0, stream>>>(part, slot_of, gate_a, out_y);
  importance_k<<<E_, 256, 0, stream>>>(out_gates, out_load, out_imp);
}

// Round 4
// 824.977 us; speedup vs baseline: 1.0199x; 1.0199x over previous
//
#include <hip/hip_runtime.h>
#include <hip/hip_bf16.h>
#include <stdint.h>

#define B_ 8192
#define D_ 1024
#define H_ 4096
#define O_ 1024
#define E_ 8

typedef __attribute__((ext_vector_type(8))) short bf16x8;
typedef __attribute__((ext_vector_type(4))) float f32x4;

__device__ __forceinline__ ushort f2bf(float f) {
  uint32_t u = __builtin_bit_cast(uint32_t, f);
  uint32_t r = (u + 0x7FFFu + ((u >> 16) & 1u)) >> 16;
  return (ushort)r;
}

__device__ __forceinline__ void gload_lds16(const ushort* g, ushort* l) {
  __builtin_amdgcn_global_load_lds(
      (__attribute__((address_space(1))) void*)g,
      (__attribute__((address_space(3))) void*)l, 16, 0, 0);
}

// ---------------- x fp32 -> bf16 ----------------
__global__ void cvt_x_k(const float* __restrict__ x, ushort* __restrict__ xb) {
  int i = blockIdx.x * 256 + threadIdx.x;            // over B*D/4
  float4 v = ((const float4*)x)[i];
  ushort4 r;
  r.x = f2bf(v.x); r.y = f2bf(v.y); r.z = f2bf(v.z); r.w = f2bf(v.w);
  ((ushort4*)xb)[i] = r;
}

// ------------- per-expert transpose + cvt: in [E][R][C] f32 -> out [E][C][R] bf16 -------------
// Transposed-store LDS (t2[c][r], pad 66: write 2-way free, read 2-way free), 4B output stores.
__global__ void transpose_cvt(const float* __restrict__ in, ushort* __restrict__ out,
                              int R, int C) {
  __shared__ ushort t2[64][66];
  int c0 = blockIdx.x * 64, r0 = blockIdx.y * 64;
  size_t eoff = (size_t)blockIdx.z * R * C;
  int t = threadIdx.x;
  int a = t & 63, q = t >> 6;
#pragma unroll
  for (int i = 0; i < 16; ++i) {
    int rl = q * 16 + i;
    t2[a][rl] = f2bf(in[eoff + (size_t)(r0 + rl) * C + c0 + a]);
  }
  __syncthreads();
#pragma unroll
  for (int i = 0; i < 8; ++i) {
    int cc = i * 8 + (t >> 5);
    int rr = (t & 31) * 2;
    *(ushort2*)&out[eoff + (size_t)(c0 + cc) * R + r0 + rr] = *(const ushort2*)&t2[cc][rr];
  }
}

// ---------------- gating: logits, top-2, softmax, routing prep ----------------
__global__ void gating_k(const float* __restrict__ x, const float* __restrict__ Wg,
                         const float* __restrict__ bg, float* __restrict__ gates,
                         float* __restrict__ topi, int* __restrict__ exp_a,
                         float* __restrict__ gate_a, int* __restrict__ counts) {
  int row = blockIdx.x * 4 + (threadIdx.x >> 6);
  int lane = threadIdx.x & 63;
  const float* xr = x + (size_t)row * D_;
  float acc[8];
#pragma unroll
  for (int e = 0; e < 8; ++e) acc[e] = 0.f;
  for (int j = 0; j < 16; ++j) {
    int d = j * 64 + lane;
    float xv = xr[d];
    const float4* wp = (const float4*)(Wg + d * 8);
    float4 w0 = wp[0], w1 = wp[1];
    acc[0] = fmaf(xv, w0.x, acc[0]); acc[1] = fmaf(xv, w0.y, acc[1]);
    acc[2] = fmaf(xv, w0.z, acc[2]); acc[3] = fmaf(xv, w0.w, acc[3]);
    acc[4] = fmaf(xv, w1.x, acc[4]); acc[5] = fmaf(xv, w1.y, acc[5]);
    acc[6] = fmaf(xv, w1.z, acc[6]); acc[7] = fmaf(xv, w1.w, acc[7]);
  }
#pragma unroll
  for (int e = 0; e < 8; ++e) {
#pragma unroll
    for (int off = 32; off; off >>= 1) acc[e] += __shfl_xor(acc[e], off);
  }
  if (lane == 0) {
    float v0 = -1e30f, v1 = -1e30f; int i0 = 0, i1 = 0;
#pragma unroll
    for (int e = 0; e < 8; ++e) {
      float ve = acc[e] + bg[e];
      if (ve > v0)      { v1 = v0; i1 = i0; v0 = ve; i0 = e; }
      else if (ve > v1) { v1 = ve; i1 = e; }
    }
    float t = expf(v1 - v0);
    float g0 = 1.f / (1.f + t), g1 = t / (1.f + t);
    gates[row * 8 + i0] = g0;
    gates[row * 8 + i1] = g1;
    topi[row * 2 + 0] = (float)i0;
    topi[row * 2 + 1] = (float)i1;
    exp_a[row * 2 + 0] = i0;
    exp_a[row * 2 + 1] = i1;
    gate_a[row * 2 + 0] = g0;
    gate_a[row * 2 + 1] = g1;
    atomicAdd(&counts[i0], 1);
    atomicAdd(&counts[i1], 1);
  }
}

__global__ void prefix_k(const int* __restrict__ counts, int* __restrict__ offs,
                         int* __restrict__ cursors) {
  if (threadIdx.x == 0) {
    int s = 0;
    for (int e = 0; e < 8; ++e) { offs[e] = s; cursors[e] = s; s += counts[e]; }
  }
}

__global__ void scatter_k(const int* __restrict__ exp_a, int* __restrict__ cursors,
                          int* __restrict__ rows, int* __restrict__ slot_of) {
  int a = blockIdx.x * 256 + threadIdx.x;            // 0..16383
  int e = exp_a[a];
  int slot = atomicAdd(&cursors[e], 1);
  rows[slot] = a >> 1;
  slot_of[a] = slot;
}

// ============ grouped expert GEMM: 256x256x64, deep-pipelined 4-phase schedule ============
// 8 waves (2M x 4N), per-wave 128x64 C. LDS = 2 buf x (A 32K + B 32K) = 128 KiB.
// A re-chunked into per-phase BANDS: chunk q = tile rows {32q..32q+31} u {128+32q..+31},
// consumed ONLY in phase q. B chunk c = rows c*64..+63, consumed only by wave-column c
// at phase 0. => stage pair (A+B chunk) for phase g at phase g-7; 3 pairs (6 loads) in
// flight across the per-tile counted vmcnt(6). WAR: stage of pair g is >=1 barrier after
// its slot's last read (phase g-8). RAW: per-wave vmcnt(6)+barrier => all waves' pairs
// for the next tile have landed before any wave reads them.
// Grid: expert = XCD (contiguous sid range), 4x4 tile supertiles mb-major so the ~32
// concurrently-resident blocks of an XCD share 4 A-panels + 4 B-panels in L2.
template <int LAYER>
__global__ __launch_bounds__(512, 2)
void moe_gemm(const ushort* __restrict__ Abase, const ushort* __restrict__ Bbase,
              const float* __restrict__ bias, ushort* __restrict__ hout,
              float* __restrict__ part, const int* __restrict__ rows,
              const int* __restrict__ counts, const int* __restrict__ offs) {
  constexpr int KD = (LAYER == 1) ? D_ : H_;   // K dim
  constexpr int ND = (LAYER == 1) ? H_ : O_;   // N dim (rows of Bt)
  constexpr int NT = KD / 64;
  constexpr int NTILE = ND / 256;              // tiles in N
  constexpr int MTILE = 32;                    // padded tiles in M
  constexpr int SNB = NTILE / 4;               // supertile columns

  // sid: expert-per-XCD contiguous + 4x4 supertile (mb-major => workers first)
  int nwg = NTILE * MTILE * E_;
  int gid = blockIdx.x + NTILE * (blockIdx.y + MTILE * blockIdx.z);
  int sid = (gid & 7) * (nwg >> 3) + (gid >> 3);
  int e = sid / (NTILE * MTILE);
  int r = sid % (NTILE * MTILE);
  int st = r >> 4, u = r & 15;
  int mb = (st / SNB) * 4 + (u >> 2);
  int nb = (st % SNB) * 4 + (u & 3);

  int cnt = counts[e];
  int m0 = mb * 256;
  if (m0 >= cnt) return;
  int n0 = nb * 256;
  int off = offs[e];

  __shared__ __align__(16) ushort lds[65536];   // 128 KiB

  int tid = threadIdx.x;
  int wid = tid >> 6, lane = tid & 63;
  int wr = wid >> 2, wc = wid & 3;              // 2M x 4N

  // --- staging source pointers ---
  int rc = tid >> 3;                            // 0..63 row-in-chunk
  int xorc = ((lane & 7) ^ (lane >> 3)) << 3;   // inverse-swizzled k-seg (elements)
  const ushort* pA[4];
  const ushort* pB[4];
#pragma unroll
  for (int c = 0; c < 4; ++c) {
    int trow = 32 * c + (rc & 31) + ((rc >> 5) << 7);   // band mapping
    int slot = m0 + trow; slot = (slot < cnt) ? slot : (cnt - 1);
    size_t arow;
    if (LAYER == 1) arow = (size_t)rows[off + slot];
    else            arow = (size_t)(off + slot);
    pA[c] = Abase + arow * KD + xorc;
    pB[c] = Bbase + ((size_t)e * ND + n0 + 64 * c + rc) * KD + xorc;
  }

  auto STAGE = [&](int g) {                      // stage pair for phase g
    int c = g & 3, bb = (g >> 2) & 1;
    ushort* base = lds + bb * 32768;
    gload_lds16(pA[c], base + c * 4096 + wid * 512);
    gload_lds16(pB[c], base + 16384 + c * 4096 + wid * 512);
    pA[c] += 64; pB[c] += 64;
  };

  f32x4 acc[8][4];
  f32x4 z = {0.f, 0.f, 0.f, 0.f};
#pragma unroll
  for (int m = 0; m < 8; ++m)
#pragma unroll
    for (int n = 0; n < 4; ++n) acc[m][n] = z;

  int lrow = lane & 15;
  int lkb = (lane >> 4) << 4;        // byte offset of 8-elem k-seg within 128B row
  int swz = (lane & 7) << 4;

  // prologue: pairs 0..6 (tile 0 + 3 pairs of tile 1), 3 pairs stay in flight
#pragma unroll
  for (int g = 0; g < 7; ++g) STAGE(g);
  asm volatile("s_waitcnt vmcnt(6)" ::: "memory");
  asm volatile("s_barrier" ::: "memory");

#pragma unroll 1
  for (int t = 0; t < NT; ++t) {
    const char* bufA = (const char*)lds + (t & 1) * 65536;
    const char* bufB = bufA + 32768;
    bf16x8 bfr[4][2];
#pragma unroll
    for (int q = 0; q < 4; ++q) {
      bf16x8 af[2][2];
#pragma unroll
      for (int mm = 0; mm < 2; ++mm)
#pragma unroll
        for (int ks = 0; ks < 2; ++ks) {
          int rr = wr * 32 + mm * 16 + lrow;     // row within band-chunk q
          af[mm][ks] = *(const bf16x8*)(bufA + q * 8192 + rr * 128 + ((ks * 64 + lkb) ^ swz));
        }
      if (q == 0) {
#pragma unroll
        for (int n = 0; n < 4; ++n)
#pragma unroll
          for (int ks = 0; ks < 2; ++ks) {
            int rr = n * 16 + lrow;
            bfr[n][ks] = *(const bf16x8*)(bufB + wc * 8192 + rr * 128 + ((ks * 64 + lkb) ^ swz));
          }
      }
      int g = 4 * t + q + 7;
      if (g < 4 * NT) STAGE(g);
      asm volatile("s_barrier" ::: "memory");
      __builtin_amdgcn_s_setprio(1);
#pragma unroll
      for (int mm = 0; mm < 2; ++mm)
#pragma unroll
        for (int n = 0; n < 4; ++n)
#pragma unroll
          for (int ks = 0; ks < 2; ++ks)
            acc[2 * q + mm][n] = __builtin_amdgcn_mfma_f32_16x16x32_bf16(
                af[mm][ks], bfr[n][ks], acc[2 * q + mm][n], 0, 0, 0);
      __builtin_amdgcn_s_setprio(0);
      if (q == 3) {
        if (t < NT - 2)       asm volatile("s_waitcnt vmcnt(6)" ::: "memory");
        else if (t == NT - 2) asm volatile("s_waitcnt vmcnt(0)" ::: "memory");
      }
      asm volatile("s_barrier" ::: "memory");
    }
  }

  // --- epilogue: C/D layout col=lane&15, row=(lane>>4)*4+j ---
  const float* bias_e = bias + (size_t)e * ND;
  int colbase = n0 + wc * 64;
#pragma unroll
  for (int m = 0; m < 8; ++m) {
    int rl2 = m0 + wr * 128 + m * 16 + ((lane >> 4) << 2);
#pragma unroll
    for (int n = 0; n < 4; ++n) {
      int cg = colbase + n * 16 + (lane & 15);
      float bv = bias_e[cg];
      f32x4 a = acc[m][n];
#pragma unroll
      for (int j = 0; j < 4; ++j) {
        int rr = rl2 + j;
        if (rr < cnt) {
          float v = a[j] + bv;
          if (LAYER == 1) {
            v = fmaxf(v, 0.f);
            hout[(size_t)(off + rr) * H_ + cg] = f2bf(v);
          } else {
            part[(size_t)(off + rr) * O_ + cg] = v;
          }
        }
      }
    }
  }
}

// ---------------- combine: out[b] = g0*part[s0] + g1*part[s1] ----------------
__global__ void combine_k(const float* __restrict__ part, const int* __restrict__ slot_of,
                          const float* __restrict__ gate_a, float* __restrict__ out) {
  int i = blockIdx.x * 256 + threadIdx.x;  // over B*O/4
  int b = i >> 8;
  int c4 = i & 255;
  int s0 = slot_of[b * 2], s1 = slot_of[b * 2 + 1];
  float g0 = gate_a[b * 2], g1 = gate_a[b * 2 + 1];
  float4 p0 = ((const float4*)(part + (size_t)s0 * O_))[c4];
  float4 p1 = ((const float4*)(part + (size_t)s1 * O_))[c4];
  float4 r;
  r.x = g0 * p0.x + g1 * p1.x;
  r.y = g0 * p0.y + g1 * p1.y;
  r.z = g0 * p0.z + g1 * p1.z;
  r.w = g0 * p0.w + g1 * p1.w;
  ((float4*)(out + (size_t)b * O_))[c4] = r;
}

// ---------------- importance / load (deterministic fixed-tree reduce) ----------------
__global__ void importance_k(const float* __restrict__ gates, float* __restrict__ load,
                             float* __restrict__ imp) {
  int e = blockIdx.x;
  float s = 0.f;
  for (int b = threadIdx.x; b < B_; b += 256) s += gates[b * 8 + e];
  __shared__ float red[4];
#pragma unroll
  for (int off = 32; off; off >>= 1) s += __shfl_xor(s, off);
  if ((threadIdx.x & 63) == 0) red[threadIdx.x >> 6] = s;
  __syncthreads();
  if (threadIdx.x == 0) {
    float t = (red[0] + red[1]) + (red[2] + red[3]);
    imp[e] = t;
    load[e] = t * (1.f / (float)B_);
  }
}

extern "C" void kernel_launch(void* const* d_in, const int* in_sizes, int n_in,
                              void* d_out, int out_size, void* d_ws, size_t ws_size,
                              hipStream_t stream) {
  const float* x  = (const float*)d_in[0];
  const float* Wg = (const float*)d_in[1];
  const float* bg = (const float*)d_in[2];
  const float* W1 = (const float*)d_in[3];
  const float* b1 = (const float*)d_in[4];
  const float* W2 = (const float*)d_in[5];
  const float* b2 = (const float*)d_in[6];

  float* out = (float*)d_out;
  float* out_y     = out;                 // [B,O]  8388608
  float* out_gates = out + 8388608;       // [B,E]  65536
  float* out_load  = out + 8454144;       // [E]    8
  float* out_imp   = out + 8454152;       // [E]    8
  float* out_topi  = out + 8454160;       // [B,K]  16384 (as float)

  char* w = (char*)d_ws;
  ushort* x_bf    = (ushort*)(w);                      // 16,777,216 B
  ushort* w1t     = (ushort*)(w + 16777216);           // 67,108,864 B  [E][H][D]
  ushort* w2t     = (ushort*)(w + 83886080);           // 67,108,864 B  [E][O][H]
  ushort* h_buf   = (ushort*)(w + 150994944);          // 134,217,728 B [16384][H]
  float*  part    = (float*)(w + 285212672);           // 67,108,864 B  [16384][O]
  int*    rows    = (int*)(w + 352321536);             // 65536 B
  int*    slot_of = (int*)(w + 352387072);             // 65536 B
  int*    exp_a   = (int*)(w + 352452608);             // 65536 B
  float*  gate_a  = (float*)(w + 352518144);           // 65536 B
  int*    counts  = (int*)(w + 352583680);             // 32 B
  int*    offs    = (int*)(w + 352583712);             // 32 B
  int*    cursors = (int*)(w + 352583744);             // 32 B

  (void)in_sizes; (void)n_in; (void)out_size; (void)ws_size;

  hipMemsetAsync(out_gates, 0, 65536 * sizeof(float), stream);
  hipMemsetAsync(counts, 0, 96, stream);

  cvt_x_k<<<B_ * D_ / 4 / 256, 256, 0, stream>>>(x, x_bf);
  transpose_cvt<<<dim3(H_ / 64, D_ / 64, E_), 256, 0, stream>>>(W1, w1t, D_, H_);
  transpose_cvt<<<dim3(O_ / 64, H_ / 64, E_), 256, 0, stream>>>(W2, w2t, H_, O_);

  gating_k<<<B_ / 4, 256, 0, stream>>>(x, Wg, bg, out_gates, out_topi, exp_a, gate_a, counts);
  prefix_k<<<1, 64, 0, stream>>>(counts, offs, cursors);
  scatter_k<<<64, 256, 0, stream>>>(exp_a, cursors, rows, slot_of);

  moe_gemm<1><<<dim3(H_ / 256, 32, E_), 512, 0, stream>>>(x_bf, w1t, b1, h_buf, part,
                                                          rows, counts, offs);
  moe_gemm<2><<<dim3(O_ / 256, 32, E_), 512, 0, stream>>>(h_buf, w2t, b2, h_buf, part,
                                                          rows, counts, offs);

  combine_k<<<B_ * O_ / 4 / 256, 256, 0, stream>>>(part, slot_of, gate_a, out_y);
  importance_k<<<E_, 256, 0, stream>>>(out_gates, out_load, out_imp);
}

// Round 5
// 621.835 us; speedup vs baseline: 1.3531x; 1.3267x over previous
//
#include <hip/hip_runtime.h>
#include <hip/hip_bf16.h>
#include <stdint.h>

#define B_ 8192
#define D_ 1024
#define H_ 4096
#define O_ 1024
#define E_ 8

typedef __attribute__((ext_vector_type(8))) short bf16x8;
typedef __attribute__((ext_vector_type(4))) float f32x4;

__device__ __forceinline__ ushort f2bf(float f) {
  uint32_t u = __builtin_bit_cast(uint32_t, f);
  uint32_t r = (u + 0x7FFFu + ((u >> 16) & 1u)) >> 16;
  return (ushort)r;
}

__device__ __forceinline__ void gload_lds16(const ushort* g, ushort* l) {
  __builtin_amdgcn_global_load_lds(
      (__attribute__((address_space(1))) void*)g,
      (__attribute__((address_space(3))) void*)l, 16, 0, 0);
}

// ------------- per-expert transpose + cvt: in [E][R][C] f32 -> out [E][C][R] bf16 -------------
// float4 reads (16B/lane), LDS pad 72 (ushort4-aligned rows, <=2-way banks), ushort4 stores.
__global__ void transpose_cvt(const float* __restrict__ in, ushort* __restrict__ out,
                              int R, int C) {
  __shared__ ushort t2[64][72];
  int c0 = blockIdx.x * 64, r0 = blockIdx.y * 64;
  size_t eoff = (size_t)blockIdx.z * R * C;
  int tid = threadIdx.x;
#pragma unroll
  for (int i = 0; i < 4; ++i) {
    int idx = i * 256 + tid;
    int r = idx >> 4, c4 = (idx & 15) * 4;
    float4 v = *(const float4*)(in + eoff + (size_t)(r0 + r) * C + c0 + c4);
    t2[c4 + 0][r] = f2bf(v.x); t2[c4 + 1][r] = f2bf(v.y);
    t2[c4 + 2][r] = f2bf(v.z); t2[c4 + 3][r] = f2bf(v.w);
  }
  __syncthreads();
#pragma unroll
  for (int i = 0; i < 4; ++i) {
    int idx = i * 256 + tid;
    int cc = idx >> 4, r4 = (idx & 15) * 4;
    *(ushort4*)&out[eoff + (size_t)(c0 + cc) * R + r0 + r4] = *(const ushort4*)&t2[cc][r4];
  }
}

// ---------------- gating: logits, top-2, softmax; fused x->bf16; NO atomics ----------------
__global__ void gating_k(const float* __restrict__ x, const float* __restrict__ Wg,
                         const float* __restrict__ bg, float* __restrict__ gates,
                         float* __restrict__ topi, int* __restrict__ exp_a,
                         float* __restrict__ gate_a, ushort* __restrict__ xb) {
  int row = blockIdx.x * 4 + (threadIdx.x >> 6);
  int lane = threadIdx.x & 63;
  const float* xr = x + (size_t)row * D_;
  ushort* xbr = xb + (size_t)row * D_;
  float acc[8];
#pragma unroll
  for (int e = 0; e < 8; ++e) acc[e] = 0.f;
  for (int j = 0; j < 16; ++j) {
    int d = j * 64 + lane;
    float xv = xr[d];
    xbr[d] = f2bf(xv);
    const float4* wp = (const float4*)(Wg + d * 8);
    float4 w0 = wp[0], w1 = wp[1];
    acc[0] = fmaf(xv, w0.x, acc[0]); acc[1] = fmaf(xv, w0.y, acc[1]);
    acc[2] = fmaf(xv, w0.z, acc[2]); acc[3] = fmaf(xv, w0.w, acc[3]);
    acc[4] = fmaf(xv, w1.x, acc[4]); acc[5] = fmaf(xv, w1.y, acc[5]);
    acc[6] = fmaf(xv, w1.z, acc[6]); acc[7] = fmaf(xv, w1.w, acc[7]);
  }
#pragma unroll
  for (int e = 0; e < 8; ++e) {
#pragma unroll
    for (int off = 32; off; off >>= 1) acc[e] += __shfl_xor(acc[e], off);
  }
  if (lane == 0) {
    float v0 = -1e30f, v1 = -1e30f; int i0 = 0, i1 = 0;
#pragma unroll
    for (int e = 0; e < 8; ++e) {
      float ve = acc[e] + bg[e];
      if (ve > v0)      { v1 = v0; i1 = i0; v0 = ve; i0 = e; }
      else if (ve > v1) { v1 = ve; i1 = e; }
    }
    float t = expf(v1 - v0);
    float g0 = 1.f / (1.f + t), g1 = t / (1.f + t);
#pragma unroll
    for (int e = 0; e < 8; ++e)
      gates[row * 8 + e] = (e == i0) ? g0 : ((e == i1) ? g1 : 0.f);
    topi[row * 2 + 0] = (float)i0;
    topi[row * 2 + 1] = (float)i1;
    exp_a[row * 2 + 0] = i0;
    exp_a[row * 2 + 1] = i1;
    gate_a[row * 2 + 0] = g0;
    gate_a[row * 2 + 1] = g1;
  }
}

// ---------------- histogram + prefix: one block, ballot-based, no global atomics ----------------
__global__ void count_prefix_k(const int* __restrict__ exp_a, int* __restrict__ counts,
                               int* __restrict__ offs, int* __restrict__ cursors) {
  __shared__ int hist[8];
  int tid = threadIdx.x, lane = tid & 63;
  if (tid < 8) hist[tid] = 0;
  __syncthreads();
  int c[8];
#pragma unroll
  for (int k = 0; k < 8; ++k) c[k] = 0;
  for (int i = tid; i < 2 * B_; i += 256) {
    int e = exp_a[i];
#pragma unroll
    for (int k = 0; k < 8; ++k) {
      unsigned long long m = __ballot(e == k);
      c[k] += (lane == 0) ? __popcll(m) : 0;
    }
  }
  if (lane == 0) {
#pragma unroll
    for (int k = 0; k < 8; ++k) atomicAdd(&hist[k], c[k]);
  }
  __syncthreads();
  if (tid == 0) {
    int s = 0;
#pragma unroll
    for (int e = 0; e < 8; ++e) {
      int ce = hist[e];
      counts[e] = ce; offs[e] = s; cursors[e] = s; s += ce;
    }
  }
}

// ---------------- scatter: wave-aggregated atomics (<=8 per wave) ----------------
__global__ void scatter_k(const int* __restrict__ exp_a, int* __restrict__ cursors,
                          int* __restrict__ rows, int* __restrict__ slot_of) {
  int a = blockIdx.x * 256 + threadIdx.x;            // 0..16383
  int lane = threadIdx.x & 63;
  int e = exp_a[a];
  unsigned long long lt = (lane == 63) ? ~0ull >> 1 : ((1ull << (lane & 63)) - 1);
  int slot = 0;
#pragma unroll
  for (int k = 0; k < 8; ++k) {
    unsigned long long m = __ballot(e == k);
    if (m) {
      int leader = __ffsll((unsigned long long)m) - 1;
      int base = 0;
      if (lane == leader) base = atomicAdd(&cursors[k], __popcll(m));
      base = __shfl(base, leader);
      if (e == k) slot = base + __popcll(m & lt);
    }
  }
  rows[slot] = a >> 1;
  slot_of[a] = slot;
}

// ============ grouped expert GEMM: 256x256x64, deep-pipelined 4-phase schedule ============
// (unchanged from R4 — verified passing, conflicts=0)
template <int LAYER>
__global__ __launch_bounds__(512, 2)
void moe_gemm(const ushort* __restrict__ Abase, const ushort* __restrict__ Bbase,
              const float* __restrict__ bias, ushort* __restrict__ hout,
              float* __restrict__ part, const int* __restrict__ rows,
              const int* __restrict__ counts, const int* __restrict__ offs) {
  constexpr int KD = (LAYER == 1) ? D_ : H_;   // K dim
  constexpr int ND = (LAYER == 1) ? H_ : O_;   // N dim (rows of Bt)
  constexpr int NT = KD / 64;
  constexpr int NTILE = ND / 256;              // tiles in N
  constexpr int MTILE = 32;                    // padded tiles in M
  constexpr int SNB = NTILE / 4;               // supertile columns

  int nwg = NTILE * MTILE * E_;
  int gid = blockIdx.x + NTILE * (blockIdx.y + MTILE * blockIdx.z);
  int sid = (gid & 7) * (nwg >> 3) + (gid >> 3);
  int e = sid / (NTILE * MTILE);
  int r = sid % (NTILE * MTILE);
  int st = r >> 4, u = r & 15;
  int mb = (st / SNB) * 4 + (u >> 2);
  int nb = (st % SNB) * 4 + (u & 3);

  int cnt = counts[e];
  int m0 = mb * 256;
  if (m0 >= cnt) return;
  int n0 = nb * 256;
  int off = offs[e];

  __shared__ __align__(16) ushort lds[65536];   // 128 KiB

  int tid = threadIdx.x;
  int wid = tid >> 6, lane = tid & 63;
  int wr = wid >> 2, wc = wid & 3;              // 2M x 4N

  int rc = tid >> 3;                            // 0..63 row-in-chunk
  int xorc = ((lane & 7) ^ (lane >> 3)) << 3;   // inverse-swizzled k-seg (elements)
  const ushort* pA[4];
  const ushort* pB[4];
#pragma unroll
  for (int c = 0; c < 4; ++c) {
    int trow = 32 * c + (rc & 31) + ((rc >> 5) << 7);   // band mapping
    int slot = m0 + trow; slot = (slot < cnt) ? slot : (cnt - 1);
    size_t arow;
    if (LAYER == 1) arow = (size_t)rows[off + slot];
    else            arow = (size_t)(off + slot);
    pA[c] = Abase + arow * KD + xorc;
    pB[c] = Bbase + ((size_t)e * ND + n0 + 64 * c + rc) * KD + xorc;
  }

  auto STAGE = [&](int g) {                      // stage pair for phase g
    int c = g & 3, bb = (g >> 2) & 1;
    ushort* base = lds + bb * 32768;
    gload_lds16(pA[c], base + c * 4096 + wid * 512);
    gload_lds16(pB[c], base + 16384 + c * 4096 + wid * 512);
    pA[c] += 64; pB[c] += 64;
  };

  f32x4 acc[8][4];
  f32x4 z = {0.f, 0.f, 0.f, 0.f};
#pragma unroll
  for (int m = 0; m < 8; ++m)
#pragma unroll
    for (int n = 0; n < 4; ++n) acc[m][n] = z;

  int lrow = lane & 15;
  int lkb = (lane >> 4) << 4;
  int swz = (lane & 7) << 4;

#pragma unroll
  for (int g = 0; g < 7; ++g) STAGE(g);
  asm volatile("s_waitcnt vmcnt(6)" ::: "memory");
  asm volatile("s_barrier" ::: "memory");

#pragma unroll 1
  for (int t = 0; t < NT; ++t) {
    const char* bufA = (const char*)lds + (t & 1) * 65536;
    const char* bufB = bufA + 32768;
    bf16x8 bfr[4][2];
#pragma unroll
    for (int q = 0; q < 4; ++q) {
      bf16x8 af[2][2];
#pragma unroll
      for (int mm = 0; mm < 2; ++mm)
#pragma unroll
        for (int ks = 0; ks < 2; ++ks) {
          int rr = wr * 32 + mm * 16 + lrow;
          af[mm][ks] = *(const bf16x8*)(bufA + q * 8192 + rr * 128 + ((ks * 64 + lkb) ^ swz));
        }
      if (q == 0) {
#pragma unroll
        for (int n = 0; n < 4; ++n)
#pragma unroll
          for (int ks = 0; ks < 2; ++ks) {
            int rr = n * 16 + lrow;
            bfr[n][ks] = *(const bf16x8*)(bufB + wc * 8192 + rr * 128 + ((ks * 64 + lkb) ^ swz));
          }
      }
      int g = 4 * t + q + 7;
      if (g < 4 * NT) STAGE(g);
      asm volatile("s_barrier" ::: "memory");
      __builtin_amdgcn_s_setprio(1);
#pragma unroll
      for (int mm = 0; mm < 2; ++mm)
#pragma unroll
        for (int n = 0; n < 4; ++n)
#pragma unroll
          for (int ks = 0; ks < 2; ++ks)
            acc[2 * q + mm][n] = __builtin_amdgcn_mfma_f32_16x16x32_bf16(
                af[mm][ks], bfr[n][ks], acc[2 * q + mm][n], 0, 0, 0);
      __builtin_amdgcn_s_setprio(0);
      if (q == 3) {
        if (t < NT - 2)       asm volatile("s_waitcnt vmcnt(6)" ::: "memory");
        else if (t == NT - 2) asm volatile("s_waitcnt vmcnt(0)" ::: "memory");
      }
      asm volatile("s_barrier" ::: "memory");
    }
  }

  const float* bias_e = bias + (size_t)e * ND;
  int colbase = n0 + wc * 64;
#pragma unroll
  for (int m = 0; m < 8; ++m) {
    int rl2 = m0 + wr * 128 + m * 16 + ((lane >> 4) << 2);
#pragma unroll
    for (int n = 0; n < 4; ++n) {
      int cg = colbase + n * 16 + (lane & 15);
      float bv = bias_e[cg];
      f32x4 a = acc[m][n];
#pragma unroll
      for (int j = 0; j < 4; ++j) {
        int rr = rl2 + j;
        if (rr < cnt) {
          float v = a[j] + bv;
          if (LAYER == 1) {
            v = fmaxf(v, 0.f);
            hout[(size_t)(off + rr) * H_ + cg] = f2bf(v);
          } else {
            part[(size_t)(off + rr) * O_ + cg] = v;
          }
        }
      }
    }
  }
}

// ---------------- combine: out[b] = g0*part[s0] + g1*part[s1] ----------------
__global__ void combine_k(const float* __restrict__ part, const int* __restrict__ slot_of,
                          const float* __restrict__ gate_a, float* __restrict__ out) {
  int i = blockIdx.x * 256 + threadIdx.x;  // over B*O/4
  int b = i >> 8;
  int c4 = i & 255;
  int s0 = slot_of[b * 2], s1 = slot_of[b * 2 + 1];
  float g0 = gate_a[b * 2], g1 = gate_a[b * 2 + 1];
  float4 p0 = ((const float4*)(part + (size_t)s0 * O_))[c4];
  float4 p1 = ((const float4*)(part + (size_t)s1 * O_))[c4];
  float4 r;
  r.x = g0 * p0.x + g1 * p1.x;
  r.y = g0 * p0.y + g1 * p1.y;
  r.z = g0 * p0.z + g1 * p1.z;
  r.w = g0 * p0.w + g1 * p1.w;
  ((float4*)(out + (size_t)b * O_))[c4] = r;
}

// ---------------- importance / load (deterministic fixed-tree reduce) ----------------
__global__ void importance_k(const float* __restrict__ gates, float* __restrict__ load,
                             float* __restrict__ imp) {
  int e = blockIdx.x;
  float s = 0.f;
  for (int b = threadIdx.x; b < B_; b += 256) s += gates[b * 8 + e];
  __shared__ float red[4];
#pragma unroll
  for (int off = 32; off; off >>= 1) s += __shfl_xor(s, off);
  if ((threadIdx.x & 63) == 0) red[threadIdx.x >> 6] = s;
  __syncthreads();
  if (threadIdx.x == 0) {
    float t = (red[0] + red[1]) + (red[2] + red[3]);
    imp[e] = t;
    load[e] = t * (1.f / (float)B_);
  }
}

extern "C" void kernel_launch(void* const* d_in, const int* in_sizes, int n_in,
                              void* d_out, int out_size, void* d_ws, size_t ws_size,
                              hipStream_t stream) {
  const float* x  = (const float*)d_in[0];
  const float* Wg = (const float*)d_in[1];
  const float* bg = (const float*)d_in[2];
  const float* W1 = (const float*)d_in[3];
  const float* b1 = (const float*)d_in[4];
  const float* W2 = (const float*)d_in[5];
  const float* b2 = (const float*)d_in[6];

  float* out = (float*)d_out;
  float* out_y     = out;                 // [B,O]  8388608
  float* out_gates = out + 8388608;       // [B,E]  65536
  float* out_load  = out + 8454144;       // [E]    8
  float* out_imp   = out + 8454152;       // [E]    8
  float* out_topi  = out + 8454160;       // [B,K]  16384 (as float)

  char* w = (char*)d_ws;
  ushort* x_bf    = (ushort*)(w);                      // 16,777,216 B
  ushort* w1t     = (ushort*)(w + 16777216);           // 67,108,864 B  [E][H][D]
  ushort* w2t     = (ushort*)(w + 83886080);           // 67,108,864 B  [E][O][H]
  ushort* h_buf   = (ushort*)(w + 150994944);          // 134,217,728 B [16384][H]
  float*  part    = (float*)(w + 285212672);           // 67,108,864 B  [16384][O]
  int*    rows    = (int*)(w + 352321536);             // 65536 B
  int*    slot_of = (int*)(w + 352387072);             // 65536 B
  int*    exp_a   = (int*)(w + 352452608);             // 65536 B
  float*  gate_a  = (float*)(w + 352518144);           // 65536 B
  int*    counts  = (int*)(w + 352583680);             // 32 B
  int*    offs    = (int*)(w + 352583712);             // 32 B
  int*    cursors = (int*)(w + 352583744);             // 32 B

  (void)in_sizes; (void)n_in; (void)out_size; (void)ws_size;

  transpose_cvt<<<dim3(H_ / 64, D_ / 64, E_), 256, 0, stream>>>(W1, w1t, D_, H_);
  transpose_cvt<<<dim3(O_ / 64, H_ / 64, E_), 256, 0, stream>>>(W2, w2t, H_, O_);

  gating_k<<<B_ / 4, 256, 0, stream>>>(x, Wg, bg, out_gates, out_topi, exp_a, gate_a, x_bf);
  count_prefix_k<<<1, 256, 0, stream>>>(exp_a, counts, offs, cursors);
  scatter_k<<<64, 256, 0, stream>>>(exp_a, cursors, rows, slot_of);

  moe_gemm<1><<<dim3(H_ / 256, 32, E_), 512, 0, stream>>>(x_bf, w1t, b1, h_buf, part,
                                                          rows, counts, offs);
  moe_gemm<2><<<dim3(O_ / 256, 32, E_), 512, 0, stream>>>(h_buf, w2t, b2, h_buf, part,
                                                          rows, counts, offs);

  combine_k<<<B_ * O_ / 4 / 256, 256, 0, stream>>>(part, slot_of, gate_a, out_y);
  importance_k<<<E_, 256, 0, stream>>>(out_gates, out_load, out_imp);
}

// Round 6
// 581.720 us; speedup vs baseline: 1.4465x; 1.0690x over previous
//
#include <hip/hip_runtime.h>
#include <hip/hip_bf16.h>
#include <stdint.h>

#define B_ 8192
#define D_ 1024
#define H_ 4096
#define O_ 1024
#define E_ 8

typedef __attribute__((ext_vector_type(8))) short bf16x8;
typedef __attribute__((ext_vector_type(4))) float f32x4;

__device__ __forceinline__ ushort f2bf(float f) {
  uint32_t u = __builtin_bit_cast(uint32_t, f);
  uint32_t r = (u + 0x7FFFu + ((u >> 16) & 1u)) >> 16;
  return (ushort)r;
}

__device__ __forceinline__ void gload_lds16(const ushort* g, ushort* l) {
  __builtin_amdgcn_global_load_lds(
      (__attribute__((address_space(1))) void*)g,
      (__attribute__((address_space(3))) void*)l, 16, 0, 0);
}

// ------------- per-expert transpose + cvt: in [E][R][C] f32 -> out [E][C][R] bf16 -------------
__global__ void transpose_cvt(const float* __restrict__ in, ushort* __restrict__ out,
                              int R, int C) {
  __shared__ ushort t2[64][72];
  int c0 = blockIdx.x * 64, r0 = blockIdx.y * 64;
  size_t eoff = (size_t)blockIdx.z * R * C;
  int tid = threadIdx.x;
#pragma unroll
  for (int i = 0; i < 4; ++i) {
    int idx = i * 256 + tid;
    int r = idx >> 4, c4 = (idx & 15) * 4;
    float4 v = *(const float4*)(in + eoff + (size_t)(r0 + r) * C + c0 + c4);
    t2[c4 + 0][r] = f2bf(v.x); t2[c4 + 1][r] = f2bf(v.y);
    t2[c4 + 2][r] = f2bf(v.z); t2[c4 + 3][r] = f2bf(v.w);
  }
  __syncthreads();
#pragma unroll
  for (int i = 0; i < 4; ++i) {
    int idx = i * 256 + tid;
    int cc = idx >> 4, r4 = (idx & 15) * 4;
    *(ushort4*)&out[eoff + (size_t)(c0 + cc) * R + r0 + r4] = *(const ushort4*)&t2[cc][r4];
  }
}

// ---------------- gating: logits, top-2, softmax; fused x->bf16; NO atomics ----------------
__global__ void gating_k(const float* __restrict__ x, const float* __restrict__ Wg,
                         const float* __restrict__ bg, float* __restrict__ gates,
                         float* __restrict__ topi, int* __restrict__ exp_a,
                         float* __restrict__ gate_a, ushort* __restrict__ xb) {
  int row = blockIdx.x * 4 + (threadIdx.x >> 6);
  int lane = threadIdx.x & 63;
  const float* xr = x + (size_t)row * D_;
  ushort* xbr = xb + (size_t)row * D_;
  float acc[8];
#pragma unroll
  for (int e = 0; e < 8; ++e) acc[e] = 0.f;
  for (int j = 0; j < 16; ++j) {
    int d = j * 64 + lane;
    float xv = xr[d];
    xbr[d] = f2bf(xv);
    const float4* wp = (const float4*)(Wg + d * 8);
    float4 w0 = wp[0], w1 = wp[1];
    acc[0] = fmaf(xv, w0.x, acc[0]); acc[1] = fmaf(xv, w0.y, acc[1]);
    acc[2] = fmaf(xv, w0.z, acc[2]); acc[3] = fmaf(xv, w0.w, acc[3]);
    acc[4] = fmaf(xv, w1.x, acc[4]); acc[5] = fmaf(xv, w1.y, acc[5]);
    acc[6] = fmaf(xv, w1.z, acc[6]); acc[7] = fmaf(xv, w1.w, acc[7]);
  }
#pragma unroll
  for (int e = 0; e < 8; ++e) {
#pragma unroll
    for (int off = 32; off; off >>= 1) acc[e] += __shfl_xor(acc[e], off);
  }
  if (lane == 0) {
    float v0 = -1e30f, v1 = -1e30f; int i0 = 0, i1 = 0;
#pragma unroll
    for (int e = 0; e < 8; ++e) {
      float ve = acc[e] + bg[e];
      if (ve > v0)      { v1 = v0; i1 = i0; v0 = ve; i0 = e; }
      else if (ve > v1) { v1 = ve; i1 = e; }
    }
    float t = expf(v1 - v0);
    float g0 = 1.f / (1.f + t), g1 = t / (1.f + t);
#pragma unroll
    for (int e = 0; e < 8; ++e)
      gates[row * 8 + e] = (e == i0) ? g0 : ((e == i1) ? g1 : 0.f);
    topi[row * 2 + 0] = (float)i0;
    topi[row * 2 + 1] = (float)i1;
    exp_a[row * 2 + 0] = i0;
    exp_a[row * 2 + 1] = i1;
    gate_a[row * 2 + 0] = g0;
    gate_a[row * 2 + 1] = g1;
  }
}

// ---------------- histogram + prefix: one block, ballot-based, no global atomics ----------------
__global__ void count_prefix_k(const int* __restrict__ exp_a, int* __restrict__ counts,
                               int* __restrict__ offs, int* __restrict__ cursors) {
  __shared__ int hist[8];
  int tid = threadIdx.x, lane = tid & 63;
  if (tid < 8) hist[tid] = 0;
  __syncthreads();
  int c[8];
#pragma unroll
  for (int k = 0; k < 8; ++k) c[k] = 0;
  for (int i = tid; i < 2 * B_; i += 256) {
    int e = exp_a[i];
#pragma unroll
    for (int k = 0; k < 8; ++k) {
      unsigned long long m = __ballot(e == k);
      c[k] += (lane == 0) ? __popcll(m) : 0;
    }
  }
  if (lane == 0) {
#pragma unroll
    for (int k = 0; k < 8; ++k) atomicAdd(&hist[k], c[k]);
  }
  __syncthreads();
  if (tid == 0) {
    int s = 0;
#pragma unroll
    for (int e = 0; e < 8; ++e) {
      int ce = hist[e];
      counts[e] = ce; offs[e] = s; cursors[e] = s; s += ce;
    }
  }
}

// ---------------- scatter: wave-aggregated atomics (<=8 per wave) ----------------
__global__ void scatter_k(const int* __restrict__ exp_a, int* __restrict__ cursors,
                          int* __restrict__ rows, int* __restrict__ slot_of) {
  int a = blockIdx.x * 256 + threadIdx.x;            // 0..16383
  int lane = threadIdx.x & 63;
  int e = exp_a[a];
  unsigned long long lt = (lane == 63) ? ~0ull >> 1 : ((1ull << (lane & 63)) - 1);
  int slot = 0;
#pragma unroll
  for (int k = 0; k < 8; ++k) {
    unsigned long long m = __ballot(e == k);
    if (m) {
      int leader = __ffsll((unsigned long long)m) - 1;
      int base = 0;
      if (lane == leader) base = atomicAdd(&cursors[k], __popcll(m));
      base = __shfl(base, leader);
      if (e == k) slot = base + __popcll(m & lt);
    }
  }
  rows[slot] = a >> 1;
  slot_of[a] = slot;
}

// ============ grouped expert GEMM: 256x256x64, deep-pipelined 4-phase schedule ============
// K-loop identical to R4/R5 (verified, conflicts=0). Epilogue: mfma args SWAPPED
// (mfma(b,a)) so C/D col(lane&15)=M-row, reg j=4 consecutive N-cols -> vector stores
// (ushort4 for L1, float4 for L2) + float4 bias loads; 128 scalar stores -> 32 vector.
template <int LAYER>
__global__ __launch_bounds__(512, 2)
void moe_gemm(const ushort* __restrict__ Abase, const ushort* __restrict__ Bbase,
              const float* __restrict__ bias, ushort* __restrict__ hout,
              float* __restrict__ part, const int* __restrict__ rows,
              const int* __restrict__ counts, const int* __restrict__ offs) {
  constexpr int KD = (LAYER == 1) ? D_ : H_;   // K dim
  constexpr int ND = (LAYER == 1) ? H_ : O_;   // N dim (rows of Bt)
  constexpr int NT = KD / 64;
  constexpr int NTILE = ND / 256;              // tiles in N
  constexpr int MTILE = 32;                    // padded tiles in M
  constexpr int SNB = NTILE / 4;               // supertile columns

  int nwg = NTILE * MTILE * E_;
  int gid = blockIdx.x + NTILE * (blockIdx.y + MTILE * blockIdx.z);
  int sid = (gid & 7) * (nwg >> 3) + (gid >> 3);
  int e = sid / (NTILE * MTILE);
  int r = sid % (NTILE * MTILE);
  int st = r >> 4, u = r & 15;
  int mb = (SNB > 0 ? (st / SNB) * 4 : 0) + (u >> 2);
  int nb = (SNB > 0 ? (st % SNB) * 4 : 0) + (u & 3);

  int cnt = counts[e];
  int m0 = mb * 256;
  if (m0 >= cnt) return;
  int n0 = nb * 256;
  int off = offs[e];

  __shared__ __align__(16) ushort lds[65536];   // 128 KiB

  int tid = threadIdx.x;
  int wid = tid >> 6, lane = tid & 63;
  int wr = wid >> 2, wc = wid & 3;              // 2M x 4N

  int rc = tid >> 3;                            // 0..63 row-in-chunk
  int xorc = ((lane & 7) ^ (lane >> 3)) << 3;   // inverse-swizzled k-seg (elements)
  const ushort* pA[4];
  const ushort* pB[4];
#pragma unroll
  for (int c = 0; c < 4; ++c) {
    int trow = 32 * c + (rc & 31) + ((rc >> 5) << 7);   // band mapping
    int slot = m0 + trow; slot = (slot < cnt) ? slot : (cnt - 1);
    size_t arow;
    if (LAYER == 1) arow = (size_t)rows[off + slot];
    else            arow = (size_t)(off + slot);
    pA[c] = Abase + arow * KD + xorc;
    pB[c] = Bbase + ((size_t)e * ND + n0 + 64 * c + rc) * KD + xorc;
  }

  auto STAGE = [&](int g) {                      // stage pair for phase g
    int c = g & 3, bb = (g >> 2) & 1;
    ushort* base = lds + bb * 32768;
    gload_lds16(pA[c], base + c * 4096 + wid * 512);
    gload_lds16(pB[c], base + 16384 + c * 4096 + wid * 512);
    pA[c] += 64; pB[c] += 64;
  };

  f32x4 acc[8][4];
  f32x4 z = {0.f, 0.f, 0.f, 0.f};
#pragma unroll
  for (int m = 0; m < 8; ++m)
#pragma unroll
    for (int n = 0; n < 4; ++n) acc[m][n] = z;

  int lrow = lane & 15;
  int lkb = (lane >> 4) << 4;
  int swz = (lane & 7) << 4;

#pragma unroll
  for (int g = 0; g < 7; ++g) STAGE(g);
  asm volatile("s_waitcnt vmcnt(6)" ::: "memory");
  asm volatile("s_barrier" ::: "memory");

#pragma unroll 1
  for (int t = 0; t < NT; ++t) {
    const char* bufA = (const char*)lds + (t & 1) * 65536;
    const char* bufB = bufA + 32768;
    bf16x8 bfr[4][2];
#pragma unroll
    for (int q = 0; q < 4; ++q) {
      bf16x8 af[2][2];
#pragma unroll
      for (int mm = 0; mm < 2; ++mm)
#pragma unroll
        for (int ks = 0; ks < 2; ++ks) {
          int rr = wr * 32 + mm * 16 + lrow;
          af[mm][ks] = *(const bf16x8*)(bufA + q * 8192 + rr * 128 + ((ks * 64 + lkb) ^ swz));
        }
      if (q == 0) {
#pragma unroll
        for (int n = 0; n < 4; ++n)
#pragma unroll
          for (int ks = 0; ks < 2; ++ks) {
            int rr = n * 16 + lrow;
            bfr[n][ks] = *(const bf16x8*)(bufB + wc * 8192 + rr * 128 + ((ks * 64 + lkb) ^ swz));
          }
      }
      int g = 4 * t + q + 7;
      if (g < 4 * NT) STAGE(g);
      asm volatile("s_barrier" ::: "memory");
      __builtin_amdgcn_s_setprio(1);
#pragma unroll
      for (int mm = 0; mm < 2; ++mm)
#pragma unroll
        for (int n = 0; n < 4; ++n)
#pragma unroll
          for (int ks = 0; ks < 2; ++ks)
            acc[2 * q + mm][n] = __builtin_amdgcn_mfma_f32_16x16x32_bf16(
                bfr[n][ks], af[mm][ks], acc[2 * q + mm][n], 0, 0, 0);
      __builtin_amdgcn_s_setprio(0);
      if (q == 3) {
        if (t < NT - 2)       asm volatile("s_waitcnt vmcnt(6)" ::: "memory");
        else if (t == NT - 2) asm volatile("s_waitcnt vmcnt(0)" ::: "memory");
      }
      asm volatile("s_barrier" ::: "memory");
    }
  }

  // --- epilogue (swapped C/D): M-row = ... + (lane&15); N-col = ... + (lane>>4)*4 + j ---
  const float* bias_e = bias + (size_t)e * ND;
  int colb = n0 + wc * 64 + ((lane >> 4) << 2);
  int rowb = m0 + wr * 128 + (lane & 15);
#pragma unroll
  for (int m = 0; m < 8; ++m) {
    int rr = rowb + m * 16;
    if (rr < cnt) {
      size_t gro = (size_t)(off + rr) * ND;
#pragma unroll
      for (int n = 0; n < 4; ++n) {
        int cg = colb + n * 16;
        float4 bv = *(const float4*)(bias_e + cg);
        f32x4 a = acc[m][n];
        if (LAYER == 1) {
          ushort4 o;
          o.x = f2bf(fmaxf(a[0] + bv.x, 0.f));
          o.y = f2bf(fmaxf(a[1] + bv.y, 0.f));
          o.z = f2bf(fmaxf(a[2] + bv.z, 0.f));
          o.w = f2bf(fmaxf(a[3] + bv.w, 0.f));
          *(ushort4*)&hout[gro + cg] = o;
        } else {
          float4 o;
          o.x = a[0] + bv.x; o.y = a[1] + bv.y;
          o.z = a[2] + bv.z; o.w = a[3] + bv.w;
          *(float4*)&part[gro + cg] = o;
        }
      }
    }
  }
}

// ---------------- combine: out[b] = g0*part[s0] + g1*part[s1] ----------------
__global__ void combine_k(const float* __restrict__ part, const int* __restrict__ slot_of,
                          const float* __restrict__ gate_a, float* __restrict__ out) {
  int i = blockIdx.x * 256 + threadIdx.x;  // over B*O/4
  int b = i >> 8;
  int c4 = i & 255;
  int s0 = slot_of[b * 2], s1 = slot_of[b * 2 + 1];
  float g0 = gate_a[b * 2], g1 = gate_a[b * 2 + 1];
  float4 p0 = ((const float4*)(part + (size_t)s0 * O_))[c4];
  float4 p1 = ((const float4*)(part + (size_t)s1 * O_))[c4];
  float4 r;
  r.x = g0 * p0.x + g1 * p1.x;
  r.y = g0 * p0.y + g1 * p1.y;
  r.z = g0 * p0.z + g1 * p1.z;
  r.w = g0 * p0.w + g1 * p1.w;
  ((float4*)(out + (size_t)b * O_))[c4] = r;
}

// ---------------- importance / load (deterministic fixed-tree reduce) ----------------
__global__ void importance_k(const float* __restrict__ gates, float* __restrict__ load,
                             float* __restrict__ imp) {
  int e = blockIdx.x;
  float s = 0.f;
  for (int b = threadIdx.x; b < B_; b += 256) s += gates[b * 8 + e];
  __shared__ float red[4];
#pragma unroll
  for (int off = 32; off; off >>= 1) s += __shfl_xor(s, off);
  if ((threadIdx.x & 63) == 0) red[threadIdx.x >> 6] = s;
  __syncthreads();
  if (threadIdx.x == 0) {
    float t = (red[0] + red[1]) + (red[2] + red[3]);
    imp[e] = t;
    load[e] = t * (1.f / (float)B_);
  }
}

extern "C" void kernel_launch(void* const* d_in, const int* in_sizes, int n_in,
                              void* d_out, int out_size, void* d_ws, size_t ws_size,
                              hipStream_t stream) {
  const float* x  = (const float*)d_in[0];
  const float* Wg = (const float*)d_in[1];
  const float* bg = (const float*)d_in[2];
  const float* W1 = (const float*)d_in[3];
  const float* b1 = (const float*)d_in[4];
  const float* W2 = (const float*)d_in[5];
  const float* b2 = (const float*)d_in[6];

  float* out = (float*)d_out;
  float* out_y     = out;                 // [B,O]  8388608
  float* out_gates = out + 8388608;       // [B,E]  65536
  float* out_load  = out + 8454144;       // [E]    8
  float* out_imp   = out + 8454152;       // [E]    8
  float* out_topi  = out + 8454160;       // [B,K]  16384 (as float)

  char* w = (char*)d_ws;
  ushort* x_bf    = (ushort*)(w);                      // 16,777,216 B
  ushort* w1t     = (ushort*)(w + 16777216);           // 67,108,864 B  [E][H][D]
  ushort* w2t     = (ushort*)(w + 83886080);           // 67,108,864 B  [E][O][H]
  ushort* h_buf   = (ushort*)(w + 150994944);          // 134,217,728 B [16384][H]
  float*  part    = (float*)(w + 285212672);           // 67,108,864 B  [16384][O]
  int*    rows    = (int*)(w + 352321536);             // 65536 B
  int*    slot_of = (int*)(w + 352387072);             // 65536 B
  int*    exp_a   = (int*)(w + 352452608);             // 65536 B
  float*  gate_a  = (float*)(w + 352518144);           // 65536 B
  int*    counts  = (int*)(w + 352583680);             // 32 B
  int*    offs    = (int*)(w + 352583712);             // 32 B
  int*    cursors = (int*)(w + 352583744);             // 32 B

  (void)in_sizes; (void)n_in; (void)out_size; (void)ws_size;

  transpose_cvt<<<dim3(H_ / 64, D_ / 64, E_), 256, 0, stream>>>(W1, w1t, D_, H_);
  transpose_cvt<<<dim3(O_ / 64, H_ / 64, E_), 256, 0, stream>>>(W2, w2t, H_, O_);

  gating_k<<<B_ / 4, 256, 0, stream>>>(x, Wg, bg, out_gates, out_topi, exp_a, gate_a, x_bf);
  count_prefix_k<<<1, 256, 0, stream>>>(exp_a, counts, offs, cursors);
  scatter_k<<<64, 256, 0, stream>>>(exp_a, cursors, rows, slot_of);

  moe_gemm<1><<<dim3(H_ / 256, 32, E_), 512, 0, stream>>>(x_bf, w1t, b1, h_buf, part,
                                                          rows, counts, offs);
  moe_gemm<2><<<dim3(O_ / 256, 32, E_), 512, 0, stream>>>(h_buf, w2t, b2, h_buf, part,
                                                          rows, counts, offs);

  combine_k<<<B_ * O_ / 4 / 256, 256, 0, stream>>>(part, slot_of, gate_a, out_y);
  importance_k<<<E_, 256, 0, stream>>>(out_gates, out_load, out_imp);
}